// Round 7
// baseline (211.046 us; speedup 1.0000x reference)
//
#include <hip/hip_runtime.h>
#include <hip/hip_bf16.h>

// Problem constants
#define BATCH 32
#define CCH   512
#define HWSZ  1024
#define RCH   256

typedef __attribute__((ext_vector_type(8))) _Float16 f16x8;
typedef __attribute__((ext_vector_type(4))) float f32x4;

__device__ __forceinline__ ushort f2h(float f) {
    _Float16 h = (_Float16)f;
    ushort u; __builtin_memcpy(&u, &h, 2);
    return u;
}

__device__ __forceinline__ void load_lds16(const void* g, void* l) {
    __builtin_amdgcn_global_load_lds((const __attribute__((address_space(1))) void*)g,
                                     (__attribute__((address_space(3))) void*)l,
                                     16, 0, 0);
}

// T1: bijective XCD-aware block swizzle (all grids divisible by 8)
__device__ __forceinline__ void xcd_swizzle(int& bx, int& by, int& bz) {
    int gx = gridDim.x, gy = gridDim.y;
    int n   = gx * gy * gridDim.z;
    int lin = bx + gx * (by + gy * bz);
    int cpx = n >> 3;
    int s = (lin & 7) * cpx + (lin >> 3);
    bx = s % gx; s /= gx;
    by = s % gy;
    bz = s / gy;
}

// ---------------- weight prep: Wk||Wp -> fp16, Wv -> fp16, stack biases
__global__ __launch_bounds__(256) void k_prep_w(
    const float* __restrict__ Wk, const float* __restrict__ bk,
    const float* __restrict__ Wp, const float* __restrict__ bp,
    const float* __restrict__ Wv,
    ushort* __restrict__ Wkp_h, ushort* __restrict__ Wv_h, float* __restrict__ bias_kp)
{
    int idx = blockIdx.x * 256 + threadIdx.x;   // over 512*512
    if (idx < 512 * 512) {
        int o = idx >> 9, c = idx & 511;
        float w = (o < 256) ? Wk[o * 512 + c] : Wp[(o - 256) * 512 + c];
        Wkp_h[idx] = f2h(w);
        Wv_h[idx]  = f2h(Wv[idx]);
        if (c == 0) bias_kp[o] = (o < 256) ? bk[o] : bp[o - 256];
    }
}

// ---------------- transpose: x[b][c][n] fp32 -> xt[b][n][c] fp16
__global__ __launch_bounds__(256) void k_transpose(
    const float* __restrict__ x, ushort* __restrict__ xt)
{
    __shared__ float tile[64][65];
    int b  = blockIdx.z;
    int c0 = blockIdx.y * 64;
    int n0 = blockIdx.x * 64;
    const float* xb = x + (size_t)b * CCH * HWSZ;
    int t  = threadIdx.x;
    int tq = t >> 6;      // 0..3
    int tl = t & 63;      // 0..63
    #pragma unroll
    for (int i = 0; i < 16; ++i) {
        int c = i * 4 + tq;
        tile[c][tl] = xb[(size_t)(c0 + c) * HWSZ + n0 + tl];
    }
    __syncthreads();
    ushort* oh = xt + (size_t)b * HWSZ * CCH;
    #pragma unroll
    for (int i = 0; i < 16; ++i) {
        int n = i * 4 + tq;
        oh[(size_t)(n0 + n) * CCH + c0 + tl] = f2h(tile[tl][n]);
    }
}

// ================= 256x256 8-phase GEMM: out = A[M,K] * B[N,K]^T (fp16, fp32 acc)
// MODE 0: KP-projection (+col bias, fp16 out)
// MODE 1: V-projection  (+row bias, fp16 out)
// MODE 2: energy -> E' = exp(acc - rowmax_tile) fp16, + gstats[z][row][q]={m,l} (outF=gstats)
// MODE 3: PV with fused softmax-combine: A-frags scaled by sc_q = exp(m_q-m_g)/l_g
//         (bias=gstats); out = x + acc*param (transposed store)
template<int MODE>
__global__ __launch_bounds__(512, 1) void k_gemm8(
    const ushort* __restrict__ A, const ushort* __restrict__ B,
    int lda, int ldb, long aBatch, long bBatch,
    float* __restrict__ outF, ushort* __restrict__ out16,
    long oBatch, int ldo,
    const float* __restrict__ bias,
    const float* __restrict__ xres, const float* __restrict__ param,
    int NT)
{
    __shared__ ushort lds[2][2][2][8192];   // 128 KiB
    __shared__ float  pstat[256][4];        // MODE2: per-row partials (per-wn)
    __shared__ float  mrow[256];            // MODE2: combined row max
    __shared__ ushort sctab[256][4];        // MODE3: fp16 scale per (row, q)
    int bx = blockIdx.x, by = blockIdx.y, bz = blockIdx.z;
    xcd_swizzle(bx, by, bz);
    const int z  = bz;
    const int m0 = bx * 256;
    const int n0 = by * 256;
    const int t    = threadIdx.x;
    const int lane = t & 63;
    const int w    = t >> 6;
    const int wm = w >> 2, wn = w & 3;      // 2 x 4 wave grid
    const int l15 = lane & 15;
    const int hi  = lane >> 4;
    const int G   = hi ^ ((lane >> 1) & 3); // read-side granule swizzle

    const ushort* Ab = A + (size_t)z * aBatch;
    const ushort* Bb = B + (size_t)z * bBatch;

    // staging constants: thread t covers row sr (i=0) and sr+128 (i=1), granule sg
    const int sr = t >> 2;
    const int sg = (t & 3) ^ ((t >> 3) & 3);

    f32x4 acc[8][4] = {};
    f16x8 a[8], b[2];
    uint2 scq[8];

    // ---- MODE3 pass-0: combine stats -> sctab
    if (MODE == 3) {
        if (t < 256) {
            const float* gs = bias + ((size_t)z * 1024 + m0 + t) * 8;
            float4 s01 = *(const float4*)gs;
            float4 s23 = *(const float4*)(gs + 4);
            float mg = fmaxf(fmaxf(s01.x, s01.z), fmaxf(s23.x, s23.z));
            float e0 = __expf(s01.x - mg), e1 = __expf(s01.z - mg);
            float e2 = __expf(s23.x - mg), e3 = __expf(s23.z - mg);
            float inv = 1.0f / (e0 * s01.y + e1 * s01.w + e2 * s23.y + e3 * s23.w);
            sctab[t][0] = f2h(e0 * inv); sctab[t][1] = f2h(e1 * inv);
            sctab[t][2] = f2h(e2 * inv); sctab[t][3] = f2h(e3 * inv);
        }
    }

#define STAGE(par, op, ks, kt) do {                                          \
        const ushort* gb_ = (op) ? Bb : Ab;                                  \
        int ld_ = (op) ? ldb : lda;                                          \
        int r0_ = (op) ? n0 : m0;                                            \
        size_t src_ = (size_t)(r0_ + sr) * ld_ + (kt) * 64 + (ks) * 32 + sg * 8; \
        load_lds16(gb_ + src_, &lds[par][op][ks][t * 8]);                    \
        load_lds16(gb_ + src_ + (size_t)128 * ld_, &lds[par][op][ks][t * 8 + 4096]); \
    } while (0)

#define LDA_(cur, ks) do {                                                   \
        _Pragma("unroll")                                                    \
        for (int mi = 0; mi < 8; ++mi)                                       \
            a[mi] = *(const f16x8*)&lds[cur][0][ks][(wm * 128 + mi * 16 + l15) * 32 + G * 8]; \
    } while (0)

#define LDB_(cur, ks, nh) do {                                               \
        _Pragma("unroll")                                                    \
        for (int ni = 0; ni < 2; ++ni)                                       \
            b[ni] = *(const f16x8*)&lds[cur][1][ks][(wn * 64 + (nh) * 32 + ni * 16 + l15) * 32 + G * 8]; \
    } while (0)

#define BAR() __builtin_amdgcn_s_barrier()

// scale fresh A-frags by sc_q (wave-uniform q = jq>>2)
#define XFORM() do {                                                         \
        int q_ = jq >> 2;                                                    \
        _Pragma("unroll")                                                    \
        for (int mi = 0; mi < 8; ++mi) {                                     \
            unsigned u_ = (q_ & 2) ? scq[mi].y : scq[mi].x;                  \
            unsigned h_ = (q_ & 1) ? (u_ >> 16) : (u_ & 0xffffu);            \
            unsigned ss_ = h_ * 0x10001u;                                    \
            unsigned* ap_ = (unsigned*)&a[mi];                               \
            _Pragma("unroll")                                                \
            for (int k_ = 0; k_ < 4; ++k_)                                   \
                asm("v_pk_mul_f16 %0, %0, %1" : "+v"(ap_[k_]) : "v"(ss_));   \
        }                                                                    \
    } while (0)

#define MFMA_BLK(nh) do {                                                    \
        asm volatile("s_waitcnt lgkmcnt(0)" ::: "memory");                   \
        __builtin_amdgcn_sched_barrier(0);                                   \
        if (MODE == 3 && (nh) == 0) XFORM();                                 \
        __builtin_amdgcn_s_setprio(1);                                       \
        _Pragma("unroll")                                                    \
        for (int mi = 0; mi < 8; ++mi) {                                     \
            acc[mi][(nh)*2+0] = __builtin_amdgcn_mfma_f32_16x16x32_f16(a[mi], b[0], acc[mi][(nh)*2+0], 0, 0, 0); \
            acc[mi][(nh)*2+1] = __builtin_amdgcn_mfma_f32_16x16x32_f16(a[mi], b[1], acc[mi][(nh)*2+1], 0, 0, 0); \
        }                                                                    \
        __builtin_amdgcn_s_setprio(0);                                       \
    } while (0)

    // prologue: stage all 4 halves of K-tile 0
    STAGE(0, 0, 0, 0); STAGE(0, 1, 0, 0); STAGE(0, 0, 1, 0); STAGE(0, 1, 1, 0);
    asm volatile("s_waitcnt vmcnt(4) lgkmcnt(0)" ::: "memory");  // lgkm: sctab writes
    BAR();
    if (MODE == 3) {
        #pragma unroll
        for (int mi = 0; mi < 8; ++mi)
            scq[mi] = *(const uint2*)&sctab[wm * 128 + mi * 16 + l15][0];
    }

    for (int j = 0; j < NT - 1; ++j) {
        int cur = j & 1, nxt = cur ^ 1;
        int jq = j;
        // q0 (ks=0, nh=0)
        STAGE(nxt, 0, 0, j + 1);
        LDA_(cur, 0); LDB_(cur, 0, 0);
        BAR();
        MFMA_BLK(0);
        BAR();
        // q1 (ks=0, nh=1)
        STAGE(nxt, 1, 0, j + 1);
        LDB_(cur, 0, 1);
        BAR();
        MFMA_BLK(1);
        asm volatile("s_waitcnt vmcnt(4)" ::: "memory");
        BAR();
        // q2 (ks=1, nh=0)
        STAGE(nxt, 0, 1, j + 1);
        LDA_(cur, 1); LDB_(cur, 1, 0);
        BAR();
        MFMA_BLK(0);
        BAR();
        // q3 (ks=1, nh=1)
        STAGE(nxt, 1, 1, j + 1);
        LDB_(cur, 1, 1);
        BAR();
        MFMA_BLK(1);
        asm volatile("s_waitcnt vmcnt(4)" ::: "memory");
        BAR();
    }
    // last K-tile (no staging)
    {
        int cur = (NT - 1) & 1;
        int jq = NT - 1;
        LDA_(cur, 0); LDB_(cur, 0, 0);
        BAR();
        MFMA_BLK(0);
        BAR();
        LDB_(cur, 0, 1);
        BAR();
        MFMA_BLK(1);
        asm volatile("s_waitcnt vmcnt(0)" ::: "memory");
        BAR();
        LDA_(cur, 1); LDB_(cur, 1, 0);
        BAR();
        MFMA_BLK(0);
        BAR();
        LDB_(cur, 1, 1);
        BAR();
        MFMA_BLK(1);
    }

    // ---------------- MODE2: in-register softmax partials + E' conversion
    if (MODE == 2) {
        // 1) per-row partial max over this wave's 64 cols
        #pragma unroll
        for (int mi = 0; mi < 8; ++mi)
            #pragma unroll
            for (int jj = 0; jj < 4; ++jj) {
                float v = fmaxf(fmaxf(acc[mi][0][jj], acc[mi][1][jj]),
                                fmaxf(acc[mi][2][jj], acc[mi][3][jj]));
                #pragma unroll
                for (int off = 1; off < 16; off <<= 1)
                    v = fmaxf(v, __shfl_xor(v, off));
                if (l15 == 0) pstat[wm * 128 + mi * 16 + hi * 4 + jj][wn] = v;
            }
        __syncthreads();
        if (t < 256) {
            float4 p4 = *(const float4*)pstat[t];
            mrow[t] = fmaxf(fmaxf(p4.x, p4.y), fmaxf(p4.z, p4.w));
        }
        __syncthreads();
        // 2) exp + per-row partial sum
        #pragma unroll
        for (int mi = 0; mi < 8; ++mi)
            #pragma unroll
            for (int jj = 0; jj < 4; ++jj) {
                float m_ = mrow[wm * 128 + mi * 16 + hi * 4 + jj];
                float s_ = 0.f;
                #pragma unroll
                for (int ni = 0; ni < 4; ++ni) {
                    float p = __expf(acc[mi][ni][jj] - m_);
                    acc[mi][ni][jj] = p;
                    s_ += p;
                }
                #pragma unroll
                for (int off = 1; off < 16; off <<= 1)
                    s_ += __shfl_xor(s_, off);
                if (l15 == 0) pstat[wm * 128 + mi * 16 + hi * 4 + jj][wn] = s_;
            }
        __syncthreads();
        if (t < 256) {
            float4 p4 = *(const float4*)pstat[t];
            float2 st;
            st.x = mrow[t];
            st.y = (p4.x + p4.y) + (p4.z + p4.w);
            *(float2*)&outF[((size_t)z * 1024 + m0 + t) * 8 + (size_t)(n0 >> 8) * 2] = st;
        }
        // 3) fall through: acc now holds E' in (0,1]
    }

    // ---------------- epilogue
    const float prm = (MODE == 3) ? param[0] : 0.f;
    #pragma unroll
    for (int mi = 0; mi < 8; ++mi) {
        #pragma unroll
        for (int ni = 0; ni < 4; ++ni) {
            int gc  = n0 + wn * 64 + (ni >> 1) * 32 + (ni & 1) * 16 + l15;
            int gr0 = m0 + wm * 128 + mi * 16 + hi * 4;
            if (MODE == 3) {
                float*       ob = outF + (size_t)z * oBatch;
                const float* xb = xres + (size_t)z * oBatch;
                size_t g = (size_t)gc * ldo + gr0;
                float4 xv = *(const float4*)&xb[g];
                float4 ov;
                ov.x = xv.x + acc[mi][ni][0] * prm;
                ov.y = xv.y + acc[mi][ni][1] * prm;
                ov.z = xv.z + acc[mi][ni][2] * prm;
                ov.w = xv.w + acc[mi][ni][3] * prm;
                *(float4*)&ob[g] = ov;
            } else {
                #pragma unroll
                for (int jj = 0; jj < 4; ++jj) {
                    int gr = gr0 + jj;
                    float v = acc[mi][ni][jj];
                    if (MODE == 0) {
                        v += bias[gc];
                        out16[(size_t)gr * ldo + gc] = f2h(v);
                    } else if (MODE == 1) {
                        v += bias[gr];
                        out16[(size_t)z * oBatch + (size_t)gr * ldo + gc] = f2h(v);
                    } else { // MODE 2: E'
                        out16[(size_t)z * oBatch + (size_t)gr * ldo + gc] = f2h(v);
                    }
                }
            }
        }
    }
#undef STAGE
#undef LDA_
#undef LDB_
#undef BAR
#undef XFORM
#undef MFMA_BLK
}

extern "C" void kernel_launch(void* const* d_in, const int* in_sizes, int n_in,
                              void* d_out, int out_size, void* d_ws, size_t ws_size,
                              hipStream_t stream)
{
    const float* x    = (const float*)d_in[0];
    const float* Wk   = (const float*)d_in[1];
    const float* bk   = (const float*)d_in[2];
    const float* Wp   = (const float*)d_in[3];
    const float* bp   = (const float*)d_in[4];
    const float* Wv   = (const float*)d_in[5];
    const float* bv   = (const float*)d_in[6];
    const float* prm  = (const float*)d_in[7];
    float* out = (float*)d_out;
    char* ws = (char*)d_ws;

    // workspace layout (bytes)
    const size_t SZ16 = (size_t)BATCH * HWSZ * CCH * 2;   // 33.55 MB
    ushort* xt    = (ushort*)(ws + 0);
    ushort* KPt   = (ushort*)(ws + SZ16);
    ushort* fv    = (ushort*)(ws + 2 * SZ16);
    ushort* E     = (ushort*)(ws + 3 * SZ16);             // E' fp16, 67.1 MB
    char* wbase   = ws + 3 * SZ16 + (size_t)BATCH * HWSZ * HWSZ * 2;
    ushort* Wkp_h = (ushort*)(wbase);
    ushort* Wv_h  = (ushort*)(wbase + 524288);
    float*  bias_kp = (float*)(wbase + 2 * 524288);
    float*  gstats  = (float*)(wbase + 3 * 524288);       // [32][1024][4][2] f32 = 1 MB

    // 1) weight prep + x transpose
    k_prep_w<<<1024, 256, 0, stream>>>(Wk, bk, Wp, bp, Wv, Wkp_h, Wv_h, bias_kp);
    k_transpose<<<dim3(16, 8, 32), 256, 0, stream>>>(x, xt);

    // 2) key/prod projection: KPt[32768,512] = xt[32768,512] * Wkp[512,512]^T
    k_gemm8<0><<<dim3(128, 2, 1), 512, 0, stream>>>(
        xt, Wkp_h, CCH, CCH, 0, 0,
        nullptr, KPt, 0, CCH,
        bias_kp, nullptr, nullptr, CCH / 64);

    // 3) value projection: fv[b][o][m] = Wv[o][c] * xt[b][m][c]^T
    k_gemm8<1><<<dim3(2, 4, 32), 512, 0, stream>>>(
        Wv_h, xt, CCH, CCH, 0, (long)HWSZ * CCH,
        nullptr, fv, (long)CCH * HWSZ, HWSZ,
        bv, nullptr, nullptr, CCH / 64);

    // 4) energy + partial softmax: E' fp16 + gstats
    k_gemm8<2><<<dim3(4, 4, 32), 512, 0, stream>>>(
        KPt, KPt + RCH, CCH, CCH,
        (long)HWSZ * CCH, (long)HWSZ * CCH,
        gstats, E, (long)HWSZ * HWSZ, HWSZ,
        nullptr, nullptr, nullptr, RCH / 64);

    // 5) PV + softmax-combine + residual: out = x + (sim x fv^T)^T * param
    k_gemm8<3><<<dim3(4, 2, 32), 512, 0, stream>>>(
        E, fv, HWSZ, HWSZ,
        (long)HWSZ * HWSZ, (long)CCH * HWSZ,
        out, nullptr, (long)CCH * HWSZ, HWSZ,
        gstats, x, prm, HWSZ / 64);
}

// Round 8
// 196.532 us; speedup vs baseline: 1.0738x; 1.0738x over previous
//
#include <hip/hip_runtime.h>
#include <hip/hip_bf16.h>

// Problem constants
#define BATCH 32
#define CCH   512
#define HWSZ  1024
#define RCH   256

typedef __attribute__((ext_vector_type(8))) _Float16 f16x8;
typedef __attribute__((ext_vector_type(4))) float f32x4;

__device__ __forceinline__ ushort f2h(float f) {
    _Float16 h = (_Float16)f;
    ushort u; __builtin_memcpy(&u, &h, 2);
    return u;
}
__device__ __forceinline__ float h2f(ushort u) {
    _Float16 h; __builtin_memcpy(&h, &u, 2);
    return (float)h;
}

__device__ __forceinline__ void load_lds16(const void* g, void* l) {
    __builtin_amdgcn_global_load_lds((const __attribute__((address_space(1))) void*)g,
                                     (__attribute__((address_space(3))) void*)l,
                                     16, 0, 0);
}

// T1: bijective XCD-aware block swizzle (all grids divisible by 8)
__device__ __forceinline__ void xcd_swizzle(int& bx, int& by, int& bz) {
    int gx = gridDim.x, gy = gridDim.y;
    int n   = gx * gy * gridDim.z;
    int lin = bx + gx * (by + gy * bz);
    int cpx = n >> 3;
    int s = (lin & 7) * cpx + (lin >> 3);
    bx = s % gx; s /= gx;
    by = s % gy;
    bz = s / gy;
}

// ---------------- weight prep: Wk||Wp -> fp16, Wv -> fp16, stack biases
__global__ __launch_bounds__(256) void k_prep_w(
    const float* __restrict__ Wk, const float* __restrict__ bk,
    const float* __restrict__ Wp, const float* __restrict__ bp,
    const float* __restrict__ Wv,
    ushort* __restrict__ Wkp_h, ushort* __restrict__ Wv_h, float* __restrict__ bias_kp)
{
    int idx = blockIdx.x * 256 + threadIdx.x;   // over 512*512
    if (idx < 512 * 512) {
        int o = idx >> 9, c = idx & 511;
        float w = (o < 256) ? Wk[o * 512 + c] : Wp[(o - 256) * 512 + c];
        Wkp_h[idx] = f2h(w);
        Wv_h[idx]  = f2h(Wv[idx]);
        if (c == 0) bias_kp[o] = (o < 256) ? bk[o] : bp[o - 256];
    }
}

// ---------------- transpose: x[b][c][n] fp32 -> xt[b][n][c] fp16
__global__ __launch_bounds__(256) void k_transpose(
    const float* __restrict__ x, ushort* __restrict__ xt)
{
    __shared__ float tile[64][65];
    int b  = blockIdx.z;
    int c0 = blockIdx.y * 64;
    int n0 = blockIdx.x * 64;
    const float* xb = x + (size_t)b * CCH * HWSZ;
    int t  = threadIdx.x;
    int tq = t >> 6;      // 0..3
    int tl = t & 63;      // 0..63
    #pragma unroll
    for (int i = 0; i < 16; ++i) {
        int c = i * 4 + tq;
        tile[c][tl] = xb[(size_t)(c0 + c) * HWSZ + n0 + tl];
    }
    __syncthreads();
    ushort* oh = xt + (size_t)b * HWSZ * CCH;
    #pragma unroll
    for (int i = 0; i < 16; ++i) {
        int n = i * 4 + tq;
        oh[(size_t)(n0 + n) * CCH + c0 + tl] = f2h(tile[tl][n]);
    }
}

// ================= 256x256 GEMM, 2-barrier K-tiles: out = A[M,K] * B[N,K]^T
// Per K-tile 4 phases; only q1/q3 end in vmcnt(4)+s_barrier (staged-slice
// visibility + parity switch). Other phases are barrier-free so waves skew
// and hide each other's ds_read/stage latency (m114 wave-overlap).
template<int MODE>
__global__ __launch_bounds__(512, 2) void k_gemm8(
    const ushort* __restrict__ A, const ushort* __restrict__ B,
    int lda, int ldb, long aBatch, long bBatch,
    float* __restrict__ outF, ushort* __restrict__ out16,
    long oBatch, int ldo,
    const float* __restrict__ bias,
    const float* __restrict__ xres, const float* __restrict__ param,
    int NT)
{
    __shared__ ushort lds[2][2][2][8192];   // 128 KiB
    int bx = blockIdx.x, by = blockIdx.y, bz = blockIdx.z;
    xcd_swizzle(bx, by, bz);
    const int z  = bz;
    const int m0 = bx * 256;
    const int n0 = by * 256;
    const int t    = threadIdx.x;
    const int lane = t & 63;
    const int w    = t >> 6;
    const int wm = w >> 2, wn = w & 3;      // 2 x 4 wave grid
    const int l15 = lane & 15;
    const int G   = (lane >> 4) ^ ((lane >> 1) & 3);  // read-side granule swizzle

    const ushort* Ab = A + (size_t)z * aBatch;
    const ushort* Bb = B + (size_t)z * bBatch;

    // staging constants: thread t covers row sr (i=0) and sr+128 (i=1), granule sg
    const int sr = t >> 2;
    const int sg = (t & 3) ^ ((t >> 3) & 3);

    f32x4 acc[8][4] = {};
    f16x8 a[8], b[2];

#define STAGE(par, op, ks, kt) do {                                          \
        const ushort* gb_ = (op) ? Bb : Ab;                                  \
        int ld_ = (op) ? ldb : lda;                                          \
        int r0_ = (op) ? n0 : m0;                                            \
        size_t src_ = (size_t)(r0_ + sr) * ld_ + (kt) * 64 + (ks) * 32 + sg * 8; \
        load_lds16(gb_ + src_, &lds[par][op][ks][t * 8]);                    \
        load_lds16(gb_ + src_ + (size_t)128 * ld_, &lds[par][op][ks][t * 8 + 4096]); \
    } while (0)

#define LDA_(cur, ks) do {                                                   \
        _Pragma("unroll")                                                    \
        for (int mi = 0; mi < 8; ++mi)                                       \
            a[mi] = *(const f16x8*)&lds[cur][0][ks][(wm * 128 + mi * 16 + l15) * 32 + G * 8]; \
    } while (0)

#define LDB_(cur, ks, nh) do {                                               \
        _Pragma("unroll")                                                    \
        for (int ni = 0; ni < 2; ++ni)                                       \
            b[ni] = *(const f16x8*)&lds[cur][1][ks][(wn * 64 + (nh) * 32 + ni * 16 + l15) * 32 + G * 8]; \
    } while (0)

#define BAR() __builtin_amdgcn_s_barrier()

#define MFMA_BLK(nh) do {                                                    \
        asm volatile("s_waitcnt lgkmcnt(0)" ::: "memory");                   \
        __builtin_amdgcn_sched_barrier(0);                                   \
        __builtin_amdgcn_s_setprio(1);                                       \
        _Pragma("unroll")                                                    \
        for (int mi = 0; mi < 8; ++mi) {                                     \
            acc[mi][(nh)*2+0] = __builtin_amdgcn_mfma_f32_16x16x32_f16(a[mi], b[0], acc[mi][(nh)*2+0], 0, 0, 0); \
            acc[mi][(nh)*2+1] = __builtin_amdgcn_mfma_f32_16x16x32_f16(a[mi], b[1], acc[mi][(nh)*2+1], 0, 0, 0); \
        }                                                                    \
        __builtin_amdgcn_s_setprio(0);                                       \
    } while (0)

    // prologue: stage all 4 halves of K-tile 0 (8 loads; 4 remain outstanding)
    STAGE(0, 0, 0, 0); STAGE(0, 1, 0, 0); STAGE(0, 0, 1, 0); STAGE(0, 1, 1, 0);
    asm volatile("s_waitcnt vmcnt(4)" ::: "memory");   // A0(0),B0(0) landed
    BAR();

    for (int j = 0; j < NT - 1; ++j) {
        int cur = j & 1, nxt = cur ^ 1;
        // q0 (ks=0, nh=0)
        STAGE(nxt, 0, 0, j + 1);
        LDA_(cur, 0); LDB_(cur, 0, 0);
        MFMA_BLK(0);
        // q1 (ks=0, nh=1)
        STAGE(nxt, 1, 0, j + 1);
        LDB_(cur, 0, 1);
        MFMA_BLK(1);
        asm volatile("s_waitcnt vmcnt(4)" ::: "memory");   // A1(j),B1(j) landed
        BAR();
        // q2 (ks=1, nh=0)
        STAGE(nxt, 0, 1, j + 1);
        LDA_(cur, 1); LDB_(cur, 1, 0);
        MFMA_BLK(0);
        // q3 (ks=1, nh=1)
        STAGE(nxt, 1, 1, j + 1);
        LDB_(cur, 1, 1);
        MFMA_BLK(1);
        asm volatile("s_waitcnt vmcnt(4)" ::: "memory");   // A0(j+1),B0(j+1) landed
        BAR();
    }
    // last K-tile (no staging; 4 loads outstanding on entry)
    {
        int cur = (NT - 1) & 1;
        LDA_(cur, 0); LDB_(cur, 0, 0);
        MFMA_BLK(0);
        LDB_(cur, 0, 1);
        MFMA_BLK(1);
        asm volatile("s_waitcnt vmcnt(0)" ::: "memory");   // A1,B1 landed
        BAR();
        LDA_(cur, 1); LDB_(cur, 1, 0);
        MFMA_BLK(0);
        LDB_(cur, 1, 1);
        MFMA_BLK(1);
    }

    // ---------------- epilogue
    const float prm = (MODE == 3) ? param[0] : 0.f;
    #pragma unroll
    for (int mi = 0; mi < 8; ++mi) {
        #pragma unroll
        for (int ni = 0; ni < 4; ++ni) {
            int gc  = n0 + wn * 64 + (ni >> 1) * 32 + (ni & 1) * 16 + l15;
            int gr0 = m0 + wm * 128 + mi * 16 + (lane >> 4) * 4;
            if (MODE == 3) {
                float*       ob = outF + (size_t)z * oBatch;
                const float* xb = xres + (size_t)z * oBatch;
                size_t g = (size_t)gc * ldo + gr0;
                float4 xv = *(const float4*)&xb[g];
                float4 ov;
                ov.x = xv.x + acc[mi][ni][0] * prm;
                ov.y = xv.y + acc[mi][ni][1] * prm;
                ov.z = xv.z + acc[mi][ni][2] * prm;
                ov.w = xv.w + acc[mi][ni][3] * prm;
                *(float4*)&ob[g] = ov;
            } else {
                #pragma unroll
                for (int jj = 0; jj < 4; ++jj) {
                    int gr = gr0 + jj;
                    float v = acc[mi][ni][jj];
                    if (MODE == 0) {
                        v += bias[gc];
                        out16[(size_t)gr * ldo + gc] = f2h(v);
                    } else if (MODE == 1) {
                        v += bias[gr];
                        out16[(size_t)z * oBatch + (size_t)gr * ldo + gc] = f2h(v);
                    } else { // MODE 2: energy -> fp16
                        out16[(size_t)z * oBatch + (size_t)gr * ldo + gc] = f2h(v);
                    }
                }
            }
        }
    }
#undef STAGE
#undef LDA_
#undef LDB_
#undef BAR
#undef MFMA_BLK
}

// ---------------- row softmax over E (fp16 in, fp16 sim out, in place)
__global__ __launch_bounds__(256) void k_softmax(ushort* __restrict__ E)
{
    int blk = blockIdx.x;            // b*1024 + n
    ushort* row = E + (size_t)blk * HWSZ;
    int t = threadIdx.x;
    ushort4 u = *(const ushort4*)&row[t * 4];
    float v0 = h2f(u.x), v1 = h2f(u.y), v2 = h2f(u.z), v3 = h2f(u.w);
    float mx = fmaxf(fmaxf(v0, v1), fmaxf(v2, v3));
    #pragma unroll
    for (int off = 1; off < 64; off <<= 1)
        mx = fmaxf(mx, __shfl_xor(mx, off));
    __shared__ float redm[4];
    __shared__ float reds[4];
    int lane = t & 63, wv = t >> 6;
    if (lane == 0) redm[wv] = mx;
    __syncthreads();
    mx = fmaxf(fmaxf(redm[0], redm[1]), fmaxf(redm[2], redm[3]));
    float e0 = __expf(v0 - mx), e1 = __expf(v1 - mx);
    float e2 = __expf(v2 - mx), e3 = __expf(v3 - mx);
    float s = (e0 + e1) + (e2 + e3);
    #pragma unroll
    for (int off = 1; off < 64; off <<= 1)
        s += __shfl_xor(s, off);
    if (lane == 0) reds[wv] = s;
    __syncthreads();
    s = (reds[0] + reds[1]) + (reds[2] + reds[3]);
    float inv = 1.0f / s;
    ushort4 o;
    o.x = f2h(e0 * inv); o.y = f2h(e1 * inv);
    o.z = f2h(e2 * inv); o.w = f2h(e3 * inv);
    *(ushort4*)&row[t * 4] = o;
}

extern "C" void kernel_launch(void* const* d_in, const int* in_sizes, int n_in,
                              void* d_out, int out_size, void* d_ws, size_t ws_size,
                              hipStream_t stream)
{
    const float* x    = (const float*)d_in[0];
    const float* Wk   = (const float*)d_in[1];
    const float* bk   = (const float*)d_in[2];
    const float* Wp   = (const float*)d_in[3];
    const float* bp   = (const float*)d_in[4];
    const float* Wv   = (const float*)d_in[5];
    const float* bv   = (const float*)d_in[6];
    const float* prm  = (const float*)d_in[7];
    float* out = (float*)d_out;
    char* ws = (char*)d_ws;

    // workspace layout (bytes)
    const size_t SZ16 = (size_t)BATCH * HWSZ * CCH * 2;   // 33.55 MB
    ushort* xt    = (ushort*)(ws + 0);
    ushort* KPt   = (ushort*)(ws + SZ16);
    ushort* fv    = (ushort*)(ws + 2 * SZ16);
    ushort* E     = (ushort*)(ws + 3 * SZ16);             // fp16, 67.1 MB
    char* wbase   = ws + 3 * SZ16 + (size_t)BATCH * HWSZ * HWSZ * 2;
    ushort* Wkp_h = (ushort*)(wbase);
    ushort* Wv_h  = (ushort*)(wbase + 524288);
    float*  bias_kp = (float*)(wbase + 2 * 524288);

    // 1) weight prep + x transpose
    k_prep_w<<<1024, 256, 0, stream>>>(Wk, bk, Wp, bp, Wv, Wkp_h, Wv_h, bias_kp);
    k_transpose<<<dim3(16, 8, 32), 256, 0, stream>>>(x, xt);

    // 2) key/prod projection: KPt[32768,512] = xt[32768,512] * Wkp[512,512]^T
    k_gemm8<0><<<dim3(128, 2, 1), 512, 0, stream>>>(
        xt, Wkp_h, CCH, CCH, 0, 0,
        nullptr, KPt, 0, CCH,
        bias_kp, nullptr, nullptr, CCH / 64);

    // 3) value projection: fv[b][o][m] = Wv[o][c] * xt[b][m][c]^T
    k_gemm8<1><<<dim3(2, 4, 32), 512, 0, stream>>>(
        Wv_h, xt, CCH, CCH, 0, (long)HWSZ * CCH,
        nullptr, fv, (long)CCH * HWSZ, HWSZ,
        bv, nullptr, nullptr, CCH / 64);

    // 4) energy: E[b][n][m] = Kt[b][n][r] * Pt[b][m][r]^T  (fp16 out)
    k_gemm8<2><<<dim3(4, 4, 32), 512, 0, stream>>>(
        KPt, KPt + RCH, CCH, CCH,
        (long)HWSZ * CCH, (long)HWSZ * CCH,
        nullptr, E, (long)HWSZ * HWSZ, HWSZ,
        nullptr, nullptr, nullptr, RCH / 64);

    // 5) softmax rows -> sim fp16 (in place)
    k_softmax<<<BATCH * HWSZ, 256, 0, stream>>>(E);

    // 6) PV + residual: att^T[n][c] = sim[n][m] * fv[c][m]^T ; out = x + att*param
    k_gemm8<3><<<dim3(4, 2, 32), 512, 0, stream>>>(
        E, fv, HWSZ, HWSZ,
        (long)HWSZ * HWSZ, (long)CCH * HWSZ,
        out, nullptr, (long)CCH * HWSZ, HWSZ,
        nullptr, x, prm, HWSZ / 64);
}

// Round 9
// 190.946 us; speedup vs baseline: 1.1053x; 1.0293x over previous
//
#include <hip/hip_runtime.h>
#include <hip/hip_bf16.h>

// Problem constants
#define BATCH 32
#define CCH   512
#define HWSZ  1024
#define RCH   256

typedef __attribute__((ext_vector_type(8))) _Float16 f16x8;
typedef __attribute__((ext_vector_type(4))) float f32x4;

__device__ __forceinline__ ushort f2h(float f) {
    _Float16 h = (_Float16)f;
    ushort u; __builtin_memcpy(&u, &h, 2);
    return u;
}
__device__ __forceinline__ float h2f(ushort u) {
    _Float16 h; __builtin_memcpy(&h, &u, 2);
    return (float)h;
}

__device__ __forceinline__ void load_lds16(const void* g, void* l) {
    __builtin_amdgcn_global_load_lds((const __attribute__((address_space(1))) void*)g,
                                     (__attribute__((address_space(3))) void*)l,
                                     16, 0, 0);
}

// T1: bijective XCD-aware block swizzle (all grids divisible by 8)
__device__ __forceinline__ void xcd_swizzle(int& bx, int& by, int& bz) {
    int gx = gridDim.x, gy = gridDim.y;
    int n   = gx * gy * gridDim.z;
    int lin = bx + gx * (by + gy * bz);
    int cpx = n >> 3;
    int s = (lin & 7) * cpx + (lin >> 3);
    bx = s % gx; s /= gx;
    by = s % gy;
    bz = s / gy;
}

// ---------------- weight prep: Wk||Wp -> fp16, Wv -> fp16, stack biases
__global__ __launch_bounds__(256) void k_prep_w(
    const float* __restrict__ Wk, const float* __restrict__ bk,
    const float* __restrict__ Wp, const float* __restrict__ bp,
    const float* __restrict__ Wv,
    ushort* __restrict__ Wkp_h, ushort* __restrict__ Wv_h, float* __restrict__ bias_kp)
{
    int idx = blockIdx.x * 256 + threadIdx.x;   // over 512*512
    if (idx < 512 * 512) {
        int o = idx >> 9, c = idx & 511;
        float w = (o < 256) ? Wk[o * 512 + c] : Wp[(o - 256) * 512 + c];
        Wkp_h[idx] = f2h(w);
        Wv_h[idx]  = f2h(Wv[idx]);
        if (c == 0) bias_kp[o] = (o < 256) ? bk[o] : bp[o - 256];
    }
}

// ---------------- transpose: x[b][c][n] fp32 -> xt[b][n][c] fp16
__global__ __launch_bounds__(256) void k_transpose(
    const float* __restrict__ x, ushort* __restrict__ xt)
{
    __shared__ float tile[64][65];
    int b  = blockIdx.z;
    int c0 = blockIdx.y * 64;
    int n0 = blockIdx.x * 64;
    const float* xb = x + (size_t)b * CCH * HWSZ;
    int t  = threadIdx.x;
    int tq = t >> 6;      // 0..3
    int tl = t & 63;      // 0..63
    #pragma unroll
    for (int i = 0; i < 16; ++i) {
        int c = i * 4 + tq;
        tile[c][tl] = xb[(size_t)(c0 + c) * HWSZ + n0 + tl];
    }
    __syncthreads();
    ushort* oh = xt + (size_t)b * HWSZ * CCH;
    #pragma unroll
    for (int i = 0; i < 16; ++i) {
        int n = i * 4 + tq;
        oh[(size_t)(n0 + n) * CCH + c0 + tl] = f2h(tile[tl][n]);
    }
}

// ================= 256x256 GEMM, 2-barrier K-tiles + per-mi counted lgkmcnt.
// q0/q2: issue b0,b1,a0..a7 (10 ds_read_b128) then interleave lgkmcnt(7-mi)
// with MFMA pairs — LDS latency hides under MFMA issue. q1/q3 as before.
// MODE 3 epilogue: LDS-staged transpose (two 128-col halves) for coalesced
// 1KB/wave x-reads and out-writes (was 4KB-strided 16B transactions).
template<int MODE>
__global__ __launch_bounds__(512, 2) void k_gemm8(
    const ushort* __restrict__ A, const ushort* __restrict__ B,
    int lda, int ldb, long aBatch, long bBatch,
    float* __restrict__ outF, ushort* __restrict__ out16,
    long oBatch, int ldo,
    const float* __restrict__ bias,
    const float* __restrict__ xres, const float* __restrict__ param,
    int NT)
{
    __shared__ ushort lds[2][2][2][8192];   // 128 KiB
    int bx = blockIdx.x, by = blockIdx.y, bz = blockIdx.z;
    xcd_swizzle(bx, by, bz);
    const int z  = bz;
    const int m0 = bx * 256;
    const int n0 = by * 256;
    const int t    = threadIdx.x;
    const int lane = t & 63;
    const int w    = t >> 6;
    const int wm = w >> 2, wn = w & 3;      // 2 x 4 wave grid
    const int l15 = lane & 15;
    const int hi  = lane >> 4;
    const int G   = hi ^ ((lane >> 1) & 3);  // read-side granule swizzle

    const ushort* Ab = A + (size_t)z * aBatch;
    const ushort* Bb = B + (size_t)z * bBatch;

    // staging constants: thread t covers row sr (i=0) and sr+128 (i=1), granule sg
    const int sr = t >> 2;
    const int sg = (t & 3) ^ ((t >> 3) & 3);

    f32x4 acc[8][4] = {};
    f16x8 a[8], b[2];

#define STAGE(par, op, ks, kt) do {                                          \
        const ushort* gb_ = (op) ? Bb : Ab;                                  \
        int ld_ = (op) ? ldb : lda;                                          \
        int r0_ = (op) ? n0 : m0;                                            \
        size_t src_ = (size_t)(r0_ + sr) * ld_ + (kt) * 64 + (ks) * 32 + sg * 8; \
        load_lds16(gb_ + src_, &lds[par][op][ks][t * 8]);                    \
        load_lds16(gb_ + src_ + (size_t)128 * ld_, &lds[par][op][ks][t * 8 + 4096]); \
    } while (0)

#define LDA_(cur, ks) do {                                                   \
        _Pragma("unroll")                                                    \
        for (int mi = 0; mi < 8; ++mi)                                       \
            a[mi] = *(const f16x8*)&lds[cur][0][ks][(wm * 128 + mi * 16 + l15) * 32 + G * 8]; \
    } while (0)

#define LDB_(cur, ks, nh) do {                                               \
        _Pragma("unroll")                                                    \
        for (int ni = 0; ni < 2; ++ni)                                       \
            b[ni] = *(const f16x8*)&lds[cur][1][ks][(wn * 64 + (nh) * 32 + ni * 16 + l15) * 32 + G * 8]; \
    } while (0)

#define BAR() __builtin_amdgcn_s_barrier()

#define WLG(N) do { asm volatile("s_waitcnt lgkmcnt(" #N ")" ::: "memory");  \
                    __builtin_amdgcn_sched_barrier(0); } while (0)

#define MM2(mi, nh) do {                                                     \
        acc[mi][(nh)*2+0] = __builtin_amdgcn_mfma_f32_16x16x32_f16(a[mi], b[0], acc[mi][(nh)*2+0], 0, 0, 0); \
        acc[mi][(nh)*2+1] = __builtin_amdgcn_mfma_f32_16x16x32_f16(a[mi], b[1], acc[mi][(nh)*2+1], 0, 0, 0); \
    } while (0)

// nh=0 phase: reads were issued in order b0,b1,a0..a7 -> counted waits
#define MFMA_PIPE() do {                                                     \
        __builtin_amdgcn_s_setprio(1);                                       \
        WLG(7); MM2(0, 0); WLG(6); MM2(1, 0); WLG(5); MM2(2, 0);             \
        WLG(4); MM2(3, 0); WLG(3); MM2(4, 0); WLG(2); MM2(5, 0);             \
        WLG(1); MM2(6, 0); WLG(0); MM2(7, 0);                                \
        __builtin_amdgcn_s_setprio(0);                                       \
    } while (0)

#define MFMA_BLK1() do {                                                     \
        WLG(0);                                                              \
        __builtin_amdgcn_s_setprio(1);                                       \
        MM2(0, 1); MM2(1, 1); MM2(2, 1); MM2(3, 1);                          \
        MM2(4, 1); MM2(5, 1); MM2(6, 1); MM2(7, 1);                          \
        __builtin_amdgcn_s_setprio(0);                                       \
    } while (0)

    // prologue: stage all 4 halves of K-tile 0 (8 loads; 4 remain outstanding)
    STAGE(0, 0, 0, 0); STAGE(0, 1, 0, 0); STAGE(0, 0, 1, 0); STAGE(0, 1, 1, 0);
    asm volatile("s_waitcnt vmcnt(4)" ::: "memory");   // A0(0),B0(0) landed
    BAR();

    for (int j = 0; j < NT - 1; ++j) {
        int cur = j & 1, nxt = cur ^ 1;
        // q0 (ks=0, nh=0)
        STAGE(nxt, 0, 0, j + 1);
        LDB_(cur, 0, 0); LDA_(cur, 0);
        MFMA_PIPE();
        // q1 (ks=0, nh=1)
        STAGE(nxt, 1, 0, j + 1);
        LDB_(cur, 0, 1);
        MFMA_BLK1();
        asm volatile("s_waitcnt vmcnt(4)" ::: "memory");   // A1(j),B1(j) landed
        BAR();
        // q2 (ks=1, nh=0)
        STAGE(nxt, 0, 1, j + 1);
        LDB_(cur, 1, 0); LDA_(cur, 1);
        MFMA_PIPE();
        // q3 (ks=1, nh=1)
        STAGE(nxt, 1, 1, j + 1);
        LDB_(cur, 1, 1);
        MFMA_BLK1();
        asm volatile("s_waitcnt vmcnt(4)" ::: "memory");   // A0(j+1),B0(j+1) landed
        BAR();
    }
    // last K-tile (no staging; 4 loads outstanding on entry)
    {
        int cur = (NT - 1) & 1;
        LDB_(cur, 0, 0); LDA_(cur, 0);
        MFMA_PIPE();
        LDB_(cur, 0, 1);
        MFMA_BLK1();
        asm volatile("s_waitcnt vmcnt(0)" ::: "memory");   // A1,B1 landed
        BAR();
        LDB_(cur, 1, 0); LDA_(cur, 1);
        MFMA_PIPE();
        LDB_(cur, 1, 1);
        MFMA_BLK1();
    }

    // ---------------- epilogue
    if (MODE == 3) {
        // LDS-staged transposed epilogue: two halves of 128 output (c) rows.
        // Wave's cols all fall in half (wn>>1). XOR swizzle nn^((cc&7)<<2)
        // keeps both ds_write_b128 and ds_read_b128 at the 8-cycle minimum.
        float* fbuf = (float*)lds;
        const float prm = param[0];
        float*       ob = outF + (size_t)z * oBatch;
        const float* xb = xres + (size_t)z * oBatch;
        #pragma unroll
        for (int h = 0; h < 2; ++h) {
            asm volatile("s_waitcnt lgkmcnt(0)" ::: "memory");
            BAR();
            if ((wn >> 1) == h) {
                #pragma unroll
                for (int mi = 0; mi < 8; ++mi)
                    #pragma unroll
                    for (int ni = 0; ni < 4; ++ni) {
                        int cc = (wn & 1) * 64 + (ni >> 1) * 32 + (ni & 1) * 16 + l15;
                        int nn = (wm * 128 + mi * 16 + hi * 4) ^ ((cc & 7) << 2);
                        *(f32x4*)&fbuf[cc * 256 + nn] = acc[mi][ni];
                    }
            }
            asm volatile("s_waitcnt lgkmcnt(0)" ::: "memory");
            BAR();
            #pragma unroll
            for (int rr = 0; rr < 16; ++rr) {
                int cc = w * 16 + rr;
                f32x4 o4 = *(const f32x4*)&fbuf[cc * 256 + ((lane * 4) ^ ((cc & 7) << 2))];
                size_t g = (size_t)(n0 + h * 128 + cc) * ldo + m0 + lane * 4;
                float4 xv = *(const float4*)&xb[g];
                float4 ov;
                ov.x = xv.x + o4[0] * prm;
                ov.y = xv.y + o4[1] * prm;
                ov.z = xv.z + o4[2] * prm;
                ov.w = xv.w + o4[3] * prm;
                *(float4*)&ob[g] = ov;
            }
        }
    } else {
        #pragma unroll
        for (int mi = 0; mi < 8; ++mi) {
            #pragma unroll
            for (int ni = 0; ni < 4; ++ni) {
                int gc  = n0 + wn * 64 + (ni >> 1) * 32 + (ni & 1) * 16 + l15;
                int gr0 = m0 + wm * 128 + mi * 16 + hi * 4;
                #pragma unroll
                for (int jj = 0; jj < 4; ++jj) {
                    int gr = gr0 + jj;
                    float v = acc[mi][ni][jj];
                    if (MODE == 0) {
                        v += bias[gc];
                        out16[(size_t)gr * ldo + gc] = f2h(v);
                    } else if (MODE == 1) {
                        v += bias[gr];
                        out16[(size_t)z * oBatch + (size_t)gr * ldo + gc] = f2h(v);
                    } else { // MODE 2: energy -> fp16
                        out16[(size_t)z * oBatch + (size_t)gr * ldo + gc] = f2h(v);
                    }
                }
            }
        }
    }
#undef STAGE
#undef LDA_
#undef LDB_
#undef BAR
#undef WLG
#undef MM2
#undef MFMA_PIPE
#undef MFMA_BLK1
}

// ---------------- row softmax over E (fp16 in, fp16 sim out, in place)
__global__ __launch_bounds__(256) void k_softmax(ushort* __restrict__ E)
{
    int blk = blockIdx.x;            // b*1024 + n
    ushort* row = E + (size_t)blk * HWSZ;
    int t = threadIdx.x;
    ushort4 u = *(const ushort4*)&row[t * 4];
    float v0 = h2f(u.x), v1 = h2f(u.y), v2 = h2f(u.z), v3 = h2f(u.w);
    float mx = fmaxf(fmaxf(v0, v1), fmaxf(v2, v3));
    #pragma unroll
    for (int off = 1; off < 64; off <<= 1)
        mx = fmaxf(mx, __shfl_xor(mx, off));
    __shared__ float redm[4];
    __shared__ float reds[4];
    int lane = t & 63, wv = t >> 6;
    if (lane == 0) redm[wv] = mx;
    __syncthreads();
    mx = fmaxf(fmaxf(redm[0], redm[1]), fmaxf(redm[2], redm[3]));
    float e0 = __expf(v0 - mx), e1 = __expf(v1 - mx);
    float e2 = __expf(v2 - mx), e3 = __expf(v3 - mx);
    float s = (e0 + e1) + (e2 + e3);
    #pragma unroll
    for (int off = 1; off < 64; off <<= 1)
        s += __shfl_xor(s, off);
    if (lane == 0) reds[wv] = s;
    __syncthreads();
    s = (reds[0] + reds[1]) + (reds[2] + reds[3]);
    float inv = 1.0f / s;
    ushort4 o;
    o.x = f2h(e0 * inv); o.y = f2h(e1 * inv);
    o.z = f2h(e2 * inv); o.w = f2h(e3 * inv);
    *(ushort4*)&row[t * 4] = o;
}

extern "C" void kernel_launch(void* const* d_in, const int* in_sizes, int n_in,
                              void* d_out, int out_size, void* d_ws, size_t ws_size,
                              hipStream_t stream)
{
    const float* x    = (const float*)d_in[0];
    const float* Wk   = (const float*)d_in[1];
    const float* bk   = (const float*)d_in[2];
    const float* Wp   = (const float*)d_in[3];
    const float* bp   = (const float*)d_in[4];
    const float* Wv   = (const float*)d_in[5];
    const float* bv   = (const float*)d_in[6];
    const float* prm  = (const float*)d_in[7];
    float* out = (float*)d_out;
    char* ws = (char*)d_ws;

    // workspace layout (bytes)
    const size_t SZ16 = (size_t)BATCH * HWSZ * CCH * 2;   // 33.55 MB
    ushort* xt    = (ushort*)(ws + 0);
    ushort* KPt   = (ushort*)(ws + SZ16);
    ushort* fv    = (ushort*)(ws + 2 * SZ16);
    ushort* E     = (ushort*)(ws + 3 * SZ16);             // fp16, 67.1 MB
    char* wbase   = ws + 3 * SZ16 + (size_t)BATCH * HWSZ * HWSZ * 2;
    ushort* Wkp_h = (ushort*)(wbase);
    ushort* Wv_h  = (ushort*)(wbase + 524288);
    float*  bias_kp = (float*)(wbase + 2 * 524288);

    // 1) weight prep + x transpose
    k_prep_w<<<1024, 256, 0, stream>>>(Wk, bk, Wp, bp, Wv, Wkp_h, Wv_h, bias_kp);
    k_transpose<<<dim3(16, 8, 32), 256, 0, stream>>>(x, xt);

    // 2) key/prod projection: KPt[32768,512] = xt[32768,512] * Wkp[512,512]^T
    k_gemm8<0><<<dim3(128, 2, 1), 512, 0, stream>>>(
        xt, Wkp_h, CCH, CCH, 0, 0,
        nullptr, KPt, 0, CCH,
        bias_kp, nullptr, nullptr, CCH / 64);

    // 3) value projection: fv[b][o][m] = Wv[o][c] * xt[b][m][c]^T
    k_gemm8<1><<<dim3(2, 4, 32), 512, 0, stream>>>(
        Wv_h, xt, CCH, CCH, 0, (long)HWSZ * CCH,
        nullptr, fv, (long)CCH * HWSZ, HWSZ,
        bv, nullptr, nullptr, CCH / 64);

    // 4) energy: E[b][n][m] = Kt[b][n][r] * Pt[b][m][r]^T  (fp16 out)
    k_gemm8<2><<<dim3(4, 4, 32), 512, 0, stream>>>(
        KPt, KPt + RCH, CCH, CCH,
        (long)HWSZ * CCH, (long)HWSZ * CCH,
        nullptr, E, (long)HWSZ * HWSZ, HWSZ,
        nullptr, nullptr, nullptr, RCH / 64);

    // 5) softmax rows -> sim fp16 (in place)
    k_softmax<<<BATCH * HWSZ, 256, 0, stream>>>(E);

    // 6) PV + residual: att^T[n][c] = sim[n][m] * fv[c][m]^T ; out = x + att*param
    k_gemm8<3><<<dim3(4, 2, 32), 512, 0, stream>>>(
        E, fv, HWSZ, HWSZ,
        (long)HWSZ * HWSZ, (long)CCH * HWSZ,
        out, nullptr, (long)CCH * HWSZ, HWSZ,
        nullptr, x, prm, HWSZ / 64);
}

// Round 10
// 190.030 us; speedup vs baseline: 1.1106x; 1.0048x over previous
//
#include <hip/hip_runtime.h>
#include <hip/hip_bf16.h>

// Problem constants
#define BATCH 32
#define CCH   512
#define HWSZ  1024
#define RCH   256

typedef __attribute__((ext_vector_type(8))) _Float16 f16x8;
typedef __attribute__((ext_vector_type(4))) float f32x4;

__device__ __forceinline__ ushort f2h(float f) {
    _Float16 h = (_Float16)f;
    ushort u; __builtin_memcpy(&u, &h, 2);
    return u;
}
__device__ __forceinline__ float h2f(ushort u) {
    _Float16 h; __builtin_memcpy(&h, &u, 2);
    return (float)h;
}

__device__ __forceinline__ void load_lds16(const void* g, void* l) {
    __builtin_amdgcn_global_load_lds((const __attribute__((address_space(1))) void*)g,
                                     (__attribute__((address_space(3))) void*)l,
                                     16, 0, 0);
}

// T1: bijective XCD-aware block swizzle (all grids divisible by 8)
__device__ __forceinline__ void xcd_swizzle(int& bx, int& by, int& bz) {
    int gx = gridDim.x, gy = gridDim.y;
    int n   = gx * gy * gridDim.z;
    int lin = bx + gx * (by + gy * bz);
    int cpx = n >> 3;
    int s = (lin & 7) * cpx + (lin >> 3);
    bx = s % gx; s /= gx;
    by = s % gy;
    bz = s / gy;
}

// ---------------- weight prep: Wk||Wp -> fp16, Wv -> fp16, stack biases
__global__ __launch_bounds__(256) void k_prep_w(
    const float* __restrict__ Wk, const float* __restrict__ bk,
    const float* __restrict__ Wp, const float* __restrict__ bp,
    const float* __restrict__ Wv,
    ushort* __restrict__ Wkp_h, ushort* __restrict__ Wv_h, float* __restrict__ bias_kp)
{
    int idx = blockIdx.x * 256 + threadIdx.x;   // over 512*512
    if (idx < 512 * 512) {
        int o = idx >> 9, c = idx & 511;
        float w = (o < 256) ? Wk[o * 512 + c] : Wp[(o - 256) * 512 + c];
        Wkp_h[idx] = f2h(w);
        Wv_h[idx]  = f2h(Wv[idx]);
        if (c == 0) bias_kp[o] = (o < 256) ? bk[o] : bp[o - 256];
    }
}

// ---------------- transpose: x[b][c][n] fp32 -> xt[b][n][c] fp16
__global__ __launch_bounds__(256) void k_transpose(
    const float* __restrict__ x, ushort* __restrict__ xt)
{
    __shared__ float tile[64][65];
    int b  = blockIdx.z;
    int c0 = blockIdx.y * 64;
    int n0 = blockIdx.x * 64;
    const float* xb = x + (size_t)b * CCH * HWSZ;
    int t  = threadIdx.x;
    int tq = t >> 6;      // 0..3
    int tl = t & 63;      // 0..63
    #pragma unroll
    for (int i = 0; i < 16; ++i) {
        int c = i * 4 + tq;
        tile[c][tl] = xb[(size_t)(c0 + c) * HWSZ + n0 + tl];
    }
    __syncthreads();
    ushort* oh = xt + (size_t)b * HWSZ * CCH;
    #pragma unroll
    for (int i = 0; i < 16; ++i) {
        int n = i * 4 + tq;
        oh[(size_t)(n0 + n) * CCH + c0 + tl] = f2h(tile[tl][n]);
    }
}

// ================= 256x256 GEMM, 2-barrier K-tiles + per-mi counted lgkmcnt.
// NO s_setprio: at 2 waves/SIMD the co-wave's ds_read burst must issue UNDER
// this wave's MFMA cluster; raising MFMA priority starves it (m190 regime).
template<int MODE>
__global__ __launch_bounds__(512, 2) void k_gemm8(
    const ushort* __restrict__ A, const ushort* __restrict__ B,
    int lda, int ldb, long aBatch, long bBatch,
    float* __restrict__ outF, ushort* __restrict__ out16,
    long oBatch, int ldo,
    const float* __restrict__ bias,
    const float* __restrict__ xres, const float* __restrict__ param,
    int NT)
{
    __shared__ ushort lds[2][2][2][8192];   // 128 KiB
    int bx = blockIdx.x, by = blockIdx.y, bz = blockIdx.z;
    xcd_swizzle(bx, by, bz);
    const int z  = bz;
    const int m0 = bx * 256;
    const int n0 = by * 256;
    const int t    = threadIdx.x;
    const int lane = t & 63;
    const int w    = t >> 6;
    const int wm = w >> 2, wn = w & 3;      // 2 x 4 wave grid
    const int l15 = lane & 15;
    const int hi  = lane >> 4;
    const int G   = hi ^ ((lane >> 1) & 3);  // read-side granule swizzle

    const ushort* Ab = A + (size_t)z * aBatch;
    const ushort* Bb = B + (size_t)z * bBatch;

    // staging constants: thread t covers row sr (i=0) and sr+128 (i=1), granule sg
    const int sr = t >> 2;
    const int sg = (t & 3) ^ ((t >> 3) & 3);

    f32x4 acc[8][4] = {};
    f16x8 a[8], b[2];

#define STAGE(par, op, ks, kt) do {                                          \
        const ushort* gb_ = (op) ? Bb : Ab;                                  \
        int ld_ = (op) ? ldb : lda;                                          \
        int r0_ = (op) ? n0 : m0;                                            \
        size_t src_ = (size_t)(r0_ + sr) * ld_ + (kt) * 64 + (ks) * 32 + sg * 8; \
        load_lds16(gb_ + src_, &lds[par][op][ks][t * 8]);                    \
        load_lds16(gb_ + src_ + (size_t)128 * ld_, &lds[par][op][ks][t * 8 + 4096]); \
    } while (0)

#define LDA_(cur, ks) do {                                                   \
        _Pragma("unroll")                                                    \
        for (int mi = 0; mi < 8; ++mi)                                       \
            a[mi] = *(const f16x8*)&lds[cur][0][ks][(wm * 128 + mi * 16 + l15) * 32 + G * 8]; \
    } while (0)

#define LDB_(cur, ks, nh) do {                                               \
        _Pragma("unroll")                                                    \
        for (int ni = 0; ni < 2; ++ni)                                       \
            b[ni] = *(const f16x8*)&lds[cur][1][ks][(wn * 64 + (nh) * 32 + ni * 16 + l15) * 32 + G * 8]; \
    } while (0)

#define BAR() __builtin_amdgcn_s_barrier()

#define WLG(N) do { asm volatile("s_waitcnt lgkmcnt(" #N ")" ::: "memory");  \
                    __builtin_amdgcn_sched_barrier(0); } while (0)

#define MM2(mi, nh) do {                                                     \
        acc[mi][(nh)*2+0] = __builtin_amdgcn_mfma_f32_16x16x32_f16(a[mi], b[0], acc[mi][(nh)*2+0], 0, 0, 0); \
        acc[mi][(nh)*2+1] = __builtin_amdgcn_mfma_f32_16x16x32_f16(a[mi], b[1], acc[mi][(nh)*2+1], 0, 0, 0); \
    } while (0)

// nh=0 phase: reads were issued in order b0,b1,a0..a7 -> counted waits
#define MFMA_PIPE() do {                                                     \
        WLG(7); MM2(0, 0); WLG(6); MM2(1, 0); WLG(5); MM2(2, 0);             \
        WLG(4); MM2(3, 0); WLG(3); MM2(4, 0); WLG(2); MM2(5, 0);             \
        WLG(1); MM2(6, 0); WLG(0); MM2(7, 0);                                \
    } while (0)

#define MFMA_BLK1() do {                                                     \
        WLG(0);                                                              \
        MM2(0, 1); MM2(1, 1); MM2(2, 1); MM2(3, 1);                          \
        MM2(4, 1); MM2(5, 1); MM2(6, 1); MM2(7, 1);                          \
    } while (0)

    // prologue: stage all 4 halves of K-tile 0 (8 loads; 4 remain outstanding)
    STAGE(0, 0, 0, 0); STAGE(0, 1, 0, 0); STAGE(0, 0, 1, 0); STAGE(0, 1, 1, 0);
    asm volatile("s_waitcnt vmcnt(4)" ::: "memory");   // A0(0),B0(0) landed
    BAR();

    for (int j = 0; j < NT - 1; ++j) {
        int cur = j & 1, nxt = cur ^ 1;
        // q0 (ks=0, nh=0)
        STAGE(nxt, 0, 0, j + 1);
        LDB_(cur, 0, 0); LDA_(cur, 0);
        MFMA_PIPE();
        // q1 (ks=0, nh=1)
        STAGE(nxt, 1, 0, j + 1);
        LDB_(cur, 0, 1);
        MFMA_BLK1();
        asm volatile("s_waitcnt vmcnt(4)" ::: "memory");   // A1(j),B1(j) landed
        BAR();
        // q2 (ks=1, nh=0)
        STAGE(nxt, 0, 1, j + 1);
        LDB_(cur, 1, 0); LDA_(cur, 1);
        MFMA_PIPE();
        // q3 (ks=1, nh=1)
        STAGE(nxt, 1, 1, j + 1);
        LDB_(cur, 1, 1);
        MFMA_BLK1();
        asm volatile("s_waitcnt vmcnt(4)" ::: "memory");   // A0(j+1),B0(j+1) landed
        BAR();
    }
    // last K-tile (no staging; 4 loads outstanding on entry)
    {
        int cur = (NT - 1) & 1;
        LDB_(cur, 0, 0); LDA_(cur, 0);
        MFMA_PIPE();
        LDB_(cur, 0, 1);
        MFMA_BLK1();
        asm volatile("s_waitcnt vmcnt(0)" ::: "memory");   // A1,B1 landed
        BAR();
        LDB_(cur, 1, 0); LDA_(cur, 1);
        MFMA_PIPE();
        LDB_(cur, 1, 1);
        MFMA_BLK1();
    }

    // ---------------- epilogue
    if (MODE == 3) {
        // LDS-staged transposed epilogue: two halves of 128 output (c) rows.
        float* fbuf = (float*)lds;
        const float prm = param[0];
        float*       ob = outF + (size_t)z * oBatch;
        const float* xb = xres + (size_t)z * oBatch;
        #pragma unroll
        for (int h = 0; h < 2; ++h) {
            asm volatile("s_waitcnt lgkmcnt(0)" ::: "memory");
            BAR();
            if ((wn >> 1) == h) {
                #pragma unroll
                for (int mi = 0; mi < 8; ++mi)
                    #pragma unroll
                    for (int ni = 0; ni < 4; ++ni) {
                        int cc = (wn & 1) * 64 + (ni >> 1) * 32 + (ni & 1) * 16 + l15;
                        int nn = (wm * 128 + mi * 16 + hi * 4) ^ ((cc & 7) << 2);
                        *(f32x4*)&fbuf[cc * 256 + nn] = acc[mi][ni];
                    }
            }
            asm volatile("s_waitcnt lgkmcnt(0)" ::: "memory");
            BAR();
            #pragma unroll
            for (int rr = 0; rr < 16; ++rr) {
                int cc = w * 16 + rr;
                f32x4 o4 = *(const f32x4*)&fbuf[cc * 256 + ((lane * 4) ^ ((cc & 7) << 2))];
                size_t g = (size_t)(n0 + h * 128 + cc) * ldo + m0 + lane * 4;
                float4 xv = *(const float4*)&xb[g];
                float4 ov;
                ov.x = xv.x + o4[0] * prm;
                ov.y = xv.y + o4[1] * prm;
                ov.z = xv.z + o4[2] * prm;
                ov.w = xv.w + o4[3] * prm;
                *(float4*)&ob[g] = ov;
            }
        }
    } else {
        #pragma unroll
        for (int mi = 0; mi < 8; ++mi) {
            #pragma unroll
            for (int ni = 0; ni < 4; ++ni) {
                int gc  = n0 + wn * 64 + (ni >> 1) * 32 + (ni & 1) * 16 + l15;
                int gr0 = m0 + wm * 128 + mi * 16 + hi * 4;
                #pragma unroll
                for (int jj = 0; jj < 4; ++jj) {
                    int gr = gr0 + jj;
                    float v = acc[mi][ni][jj];
                    if (MODE == 0) {
                        v += bias[gc];
                        out16[(size_t)gr * ldo + gc] = f2h(v);
                    } else if (MODE == 1) {
                        v += bias[gr];
                        out16[(size_t)z * oBatch + (size_t)gr * ldo + gc] = f2h(v);
                    } else { // MODE 2: energy -> fp16
                        out16[(size_t)z * oBatch + (size_t)gr * ldo + gc] = f2h(v);
                    }
                }
            }
        }
    }
#undef STAGE
#undef LDA_
#undef LDB_
#undef BAR
#undef WLG
#undef MM2
#undef MFMA_PIPE
#undef MFMA_BLK1
}

// ---------------- row softmax over E (fp16 in, fp16 sim out, in place)
__global__ __launch_bounds__(256) void k_softmax(ushort* __restrict__ E)
{
    int blk = blockIdx.x;            // b*1024 + n
    ushort* row = E + (size_t)blk * HWSZ;
    int t = threadIdx.x;
    ushort4 u = *(const ushort4*)&row[t * 4];
    float v0 = h2f(u.x), v1 = h2f(u.y), v2 = h2f(u.z), v3 = h2f(u.w);
    float mx = fmaxf(fmaxf(v0, v1), fmaxf(v2, v3));
    #pragma unroll
    for (int off = 1; off < 64; off <<= 1)
        mx = fmaxf(mx, __shfl_xor(mx, off));
    __shared__ float redm[4];
    __shared__ float reds[4];
    int lane = t & 63, wv = t >> 6;
    if (lane == 0) redm[wv] = mx;
    __syncthreads();
    mx = fmaxf(fmaxf(redm[0], redm[1]), fmaxf(redm[2], redm[3]));
    float e0 = __expf(v0 - mx), e1 = __expf(v1 - mx);
    float e2 = __expf(v2 - mx), e3 = __expf(v3 - mx);
    float s = (e0 + e1) + (e2 + e3);
    #pragma unroll
    for (int off = 1; off < 64; off <<= 1)
        s += __shfl_xor(s, off);
    if (lane == 0) reds[wv] = s;
    __syncthreads();
    s = (reds[0] + reds[1]) + (reds[2] + reds[3]);
    float inv = 1.0f / s;
    ushort4 o;
    o.x = f2h(e0 * inv); o.y = f2h(e1 * inv);
    o.z = f2h(e2 * inv); o.w = f2h(e3 * inv);
    *(ushort4*)&row[t * 4] = o;
}

extern "C" void kernel_launch(void* const* d_in, const int* in_sizes, int n_in,
                              void* d_out, int out_size, void* d_ws, size_t ws_size,
                              hipStream_t stream)
{
    const float* x    = (const float*)d_in[0];
    const float* Wk   = (const float*)d_in[1];
    const float* bk   = (const float*)d_in[2];
    const float* Wp   = (const float*)d_in[3];
    const float* bp   = (const float*)d_in[4];
    const float* Wv   = (const float*)d_in[5];
    const float* bv   = (const float*)d_in[6];
    const float* prm  = (const float*)d_in[7];
    float* out = (float*)d_out;
    char* ws = (char*)d_ws;

    // workspace layout (bytes)
    const size_t SZ16 = (size_t)BATCH * HWSZ * CCH * 2;   // 33.55 MB
    ushort* xt    = (ushort*)(ws + 0);
    ushort* KPt   = (ushort*)(ws + SZ16);
    ushort* fv    = (ushort*)(ws + 2 * SZ16);
    ushort* E     = (ushort*)(ws + 3 * SZ16);             // fp16, 67.1 MB
    char* wbase   = ws + 3 * SZ16 + (size_t)BATCH * HWSZ * HWSZ * 2;
    ushort* Wkp_h = (ushort*)(wbase);
    ushort* Wv_h  = (ushort*)(wbase + 524288);
    float*  bias_kp = (float*)(wbase + 2 * 524288);

    // 1) weight prep + x transpose
    k_prep_w<<<1024, 256, 0, stream>>>(Wk, bk, Wp, bp, Wv, Wkp_h, Wv_h, bias_kp);
    k_transpose<<<dim3(16, 8, 32), 256, 0, stream>>>(x, xt);

    // 2) key/prod projection: KPt[32768,512] = xt[32768,512] * Wkp[512,512]^T
    k_gemm8<0><<<dim3(128, 2, 1), 512, 0, stream>>>(
        xt, Wkp_h, CCH, CCH, 0, 0,
        nullptr, KPt, 0, CCH,
        bias_kp, nullptr, nullptr, CCH / 64);

    // 3) value projection: fv[b][o][m] = Wv[o][c] * xt[b][m][c]^T
    k_gemm8<1><<<dim3(2, 4, 32), 512, 0, stream>>>(
        Wv_h, xt, CCH, CCH, 0, (long)HWSZ * CCH,
        nullptr, fv, (long)CCH * HWSZ, HWSZ,
        bv, nullptr, nullptr, CCH / 64);

    // 4) energy: E[b][n][m] = Kt[b][n][r] * Pt[b][m][r]^T  (fp16 out)
    k_gemm8<2><<<dim3(4, 4, 32), 512, 0, stream>>>(
        KPt, KPt + RCH, CCH, CCH,
        (long)HWSZ * CCH, (long)HWSZ * CCH,
        nullptr, E, (long)HWSZ * HWSZ, HWSZ,
        nullptr, nullptr, nullptr, RCH / 64);

    // 5) softmax rows -> sim fp16 (in place)
    k_softmax<<<BATCH * HWSZ, 256, 0, stream>>>(E);

    // 6) PV + residual: att^T[n][c] = sim[n][m] * fv[c][m]^T ; out = x + att*param
    k_gemm8<3><<<dim3(4, 2, 32), 512, 0, stream>>>(
        E, fv, HWSZ, HWSZ,
        (long)HWSZ * HWSZ, (long)CCH * HWSZ,
        out, nullptr, (long)CCH * HWSZ, HWSZ,
        nullptr, x, prm, HWSZ / 64);
}